// Round 8
// baseline (1255.145 us; speedup 1.0000x reference)
//
#include <hip/hip_runtime.h>
#include <hip/hip_bf16.h>

#define B_   2
#define T_   2048
#define DM   2048
#define H_   16
#define DK_  128
#define DV_  128
#define CDIM 6144
#define EPSF 1e-6f
#define CGRP 16   // scan: timesteps staged per LDS group

typedef __hip_bfloat16 bf16;
typedef short bf16x8 __attribute__((ext_vector_type(8)));
typedef float f32x4 __attribute__((ext_vector_type(4)));

// ---- workspace layout (bytes); peak = 227,540,992 < proven-OK 228,589,568 --
#define FLAG_OFF   0
#define DT_OFF     1024
#define AL_OFF     2048
#define NW_OFF     4096
#define CW_OFF     8192          // 98,304 B -> 106,496
#define WBF_OFF    131072        // f32 131,072 -> 262,144
#define WAF_OFF    262144        // -> 393,216
#define BETA_OFF   393216        // 262,144 -> 655,360
#define DEC_OFF    655360        // -> 917,504
#define XH_OFF     1048576       // 16,777,216 -> 17,825,792
#define XL_OFF     17825792      // -> 34,603,008
#define WQH_OFF    34603008      // 25,165,824 -> 59,768,832
#define WQL_OFF    59768832      // -> 84,934,656
#define WZ_OFF     84934656      // 8,388,608 -> 93,323,264
#define MIX_OFF    101711872     // f32 100,663,296 -> 202,375,168
#define WOUT_OFF   202375168     // 8,388,608 -> 210,763,776
#define Z_OFF      210763776     // bf16 16,777,216 -> 227,540,992 (peak)
#define Y_OFF      1048576       // f32 100,663,296 -> 101,711,872 (overlay)
#define O_OFF      101711872     // f32 33,554,432 -> 135,266,304 (over MIX)
#define ONH_OFF    1048576       // 16,777,216 -> 17,825,792 (over dead Y)
#define ONL_OFF    17825792      // -> 34,603,008

__device__ inline float bf2f(unsigned int u) {
  union { unsigned int i; float f; } v; v.i = u << 16; return v.f;
}
__device__ inline void up8(uint4 p, float* d) {
  d[0] = bf2f(p.x & 0xffffu); d[1] = bf2f(p.x >> 16);
  d[2] = bf2f(p.y & 0xffffu); d[3] = bf2f(p.y >> 16);
  d[4] = bf2f(p.z & 0xffffu); d[5] = bf2f(p.z >> 16);
  d[6] = bf2f(p.w & 0xffffu); d[7] = bf2f(p.w >> 16);
}
__device__ inline void gl2lds16(const bf16* g, bf16* lds) {
  __builtin_amdgcn_global_load_lds(
      (const __attribute__((address_space(1))) unsigned int*)g,
      (__attribute__((address_space(3))) unsigned int*)lds, 16, 0, 0);
}

// DPP butterfly add levels (within 16-lane rows), then shfl for xor16.
template <int CTRL>
__device__ inline float radd(float v) {
  int t = __builtin_amdgcn_update_dpp(0, __float_as_int(v), CTRL, 0xF, 0xF, true);
  return v + __int_as_float(t);
}
__device__ inline float row_sum32(float v) {
  v = radd<0xB1>(v);   // quad_perm [1,0,3,2] : + xor1
  v = radd<0x4E>(v);   // quad_perm [2,3,0,1] : + xor2
  v = radd<0x141>(v);  // row_half_mirror     : + xor4
  v = radd<0x140>(v);  // row_mirror          : + xor8
  v += __shfl_xor(v, 16);  // cross 16-lane rows within the 32-lane group
  return v;
}

// ---------------- dtype detector: flag=1 if inputs are f32 -----------------
__global__ __launch_bounds__(256) void detect_dtype(
    const unsigned short* __restrict__ xh, int* __restrict__ flag) {
  __shared__ int cnt;
  if (threadIdx.x == 0) cnt = 0;
  __syncthreads();
  int c = 0;
  for (int i = threadIdx.x; i < 8192; i += 256) {
    unsigned int e = (xh[i] >> 7) & 0xFFu;
    if (e > 140u) c++;
  }
  atomicAdd(&cnt, c);
  __syncthreads();
  if (threadIdx.x == 0) *flag = (cnt > 512) ? 1 : 0;
}

// ---------------- canonicalize kernels -------------------------------------
__global__ __launch_bounds__(256) void canon_f32(
    const void* __restrict__ in, float* __restrict__ out, int n,
    const int* __restrict__ flag) {
  const int i = (blockIdx.x * 256 + threadIdx.x) * 8;
  if (i >= n) return;
  if (*flag) {
    const float* f = (const float*)in;
    *(float4*)(out + i)     = *(const float4*)(f + i);
    *(float4*)(out + i + 4) = *(const float4*)(f + i + 4);
  } else {
    uint4 p = *(const uint4*)((const bf16*)in + i);
    float d[8]; up8(p, d);
    *(float4*)(out + i)     = *(const float4*)(d);
    *(float4*)(out + i + 4) = *(const float4*)(d + 4);
  }
}

__global__ __launch_bounds__(256) void canon_bf16(
    const void* __restrict__ in, bf16* __restrict__ out, int n,
    const int* __restrict__ flag) {
  const int i = (blockIdx.x * 256 + threadIdx.x) * 8;
  if (i >= n) return;
  if (*flag) {
    const float* f = (const float*)in;
    float4 a = *(const float4*)(f + i);
    float4 b = *(const float4*)(f + i + 4);
    bf16 t[8];
    t[0] = __float2bfloat16(a.x); t[1] = __float2bfloat16(a.y);
    t[2] = __float2bfloat16(a.z); t[3] = __float2bfloat16(a.w);
    t[4] = __float2bfloat16(b.x); t[5] = __float2bfloat16(b.y);
    t[6] = __float2bfloat16(b.z); t[7] = __float2bfloat16(b.w);
    *(uint4*)(out + i) = *(const uint4*)t;
  } else {
    *(uint4*)(out + i) = *(const uint4*)((const bf16*)in + i);
  }
}

// any-dtype -> (hi, lo) bf16 planes; hi+lo ~= x to ~17 bits
__global__ __launch_bounds__(256) void canon_split(
    const void* __restrict__ in, bf16* __restrict__ hi,
    bf16* __restrict__ lo, int n, const int* __restrict__ flag) {
  const int i = (blockIdx.x * 256 + threadIdx.x) * 8;
  if (i >= n) return;
  float v[8];
  if (*flag) {
    const float* f = (const float*)in;
    *(float4*)(v)     = *(const float4*)(f + i);
    *(float4*)(v + 4) = *(const float4*)(f + i + 4);
  } else {
    up8(*(const uint4*)((const bf16*)in + i), v);
  }
  bf16 th[8], tl[8];
#pragma unroll
  for (int j = 0; j < 8; j++) {
    th[j] = __float2bfloat16(v[j]);
    tl[j] = __float2bfloat16(v[j] - __bfloat162float(th[j]));
  }
  *(uint4*)(hi + i) = *(const uint4*)th;
  *(uint4*)(lo + i) = *(const uint4*)tl;
}

// -------- GEMM split x split: C = (Ah+Al)(Bh+Bl)^T (3-term), f32 out -------
__global__ __launch_bounds__(256) void gemm_ss(
    const bf16* __restrict__ Ah, const bf16* __restrict__ Al,
    const bf16* __restrict__ Bh, const bf16* __restrict__ Bl,
    float* __restrict__ C, int M, int N, int K) {
  __shared__ __align__(16) bf16 sAh[128 * 32];
  __shared__ __align__(16) bf16 sAl[128 * 32];
  __shared__ __align__(16) bf16 sBh[128 * 32];
  __shared__ __align__(16) bf16 sBl[128 * 32];
  const int tid  = threadIdx.x;
  const int wave = tid >> 6;
  const int lane = tid & 63;
  const int m0 = blockIdx.y * 128;
  const int n0 = blockIdx.x * 128;
  const int wm = (wave >> 1) * 64;
  const int wn = (wave & 1) * 64;
  const int lrow = lane & 15;
  const int kq   = lane >> 4;

  f32x4 acc[4][4];
#pragma unroll
  for (int i = 0; i < 4; i++)
#pragma unroll
    for (int j = 0; j < 4; j++) acc[i][j] = (f32x4){0.f, 0.f, 0.f, 0.f};

  const int row0 = tid >> 2;
  const int cb   = (tid & 3) * 8;
  const size_t aoff = (size_t)(m0 + row0) * K + cb;
  const size_t boff = (size_t)(n0 + row0) * K + cb;

  for (int k0 = 0; k0 < K; k0 += 32) {
    gl2lds16(Ah + aoff + k0,                  sAh + wave * 512);
    gl2lds16(Ah + aoff + k0 + (size_t)64 * K, sAh + 2048 + wave * 512);
    gl2lds16(Al + aoff + k0,                  sAl + wave * 512);
    gl2lds16(Al + aoff + k0 + (size_t)64 * K, sAl + 2048 + wave * 512);
    gl2lds16(Bh + boff + k0,                  sBh + wave * 512);
    gl2lds16(Bh + boff + k0 + (size_t)64 * K, sBh + 2048 + wave * 512);
    gl2lds16(Bl + boff + k0,                  sBl + wave * 512);
    gl2lds16(Bl + boff + k0 + (size_t)64 * K, sBl + 2048 + wave * 512);
    __syncthreads();

    bf16x8 afh[4], afl[4], bfh[4], bfl[4];
#pragma unroll
    for (int i = 0; i < 4; i++) {
      const int ao = (wm + i * 16 + lrow) * 32 + kq * 8;
      const int bo = (wn + i * 16 + lrow) * 32 + kq * 8;
      afh[i] = *(const bf16x8*)(sAh + ao);
      afl[i] = *(const bf16x8*)(sAl + ao);
      bfh[i] = *(const bf16x8*)(sBh + bo);
      bfl[i] = *(const bf16x8*)(sBl + bo);
    }
#pragma unroll
    for (int i = 0; i < 4; i++)
#pragma unroll
      for (int j = 0; j < 4; j++) {
        acc[i][j] = __builtin_amdgcn_mfma_f32_16x16x32_bf16(afh[i], bfh[j], acc[i][j], 0, 0, 0);
        acc[i][j] = __builtin_amdgcn_mfma_f32_16x16x32_bf16(afh[i], bfl[j], acc[i][j], 0, 0, 0);
        acc[i][j] = __builtin_amdgcn_mfma_f32_16x16x32_bf16(afl[i], bfh[j], acc[i][j], 0, 0, 0);
      }
    __syncthreads();
  }

#pragma unroll
  for (int i = 0; i < 4; i++) {
    const int r0 = m0 + wm + i * 16 + kq * 4;
#pragma unroll
    for (int j = 0; j < 4; j++) {
      const int c = n0 + wn + j * 16 + lrow;
#pragma unroll
      for (int r = 0; r < 4; r++)
        C[(size_t)(r0 + r) * N + c] = acc[i][j][r];
    }
  }
}

// -------- GEMM split-A x single-B: C = (Ah+Al)B^T. OMODE 0: bf16, 2: dual --
template <int OMODE>
__global__ __launch_bounds__(256) void gemm_bt_split(
    const bf16* __restrict__ Ah, const bf16* __restrict__ Al,
    const bf16* __restrict__ Bm, void* __restrict__ C,
    int M, int N, int K, const int* __restrict__ flag) {
  __shared__ __align__(16) bf16 sAh[128 * 32];
  __shared__ __align__(16) bf16 sAl[128 * 32];
  __shared__ __align__(16) bf16 sB[128 * 32];
  const int tid  = threadIdx.x;
  const int wave = tid >> 6;
  const int lane = tid & 63;
  const int m0 = blockIdx.y * 128;
  const int n0 = blockIdx.x * 128;
  const int wm = (wave >> 1) * 64;
  const int wn = (wave & 1) * 64;
  const int lrow = lane & 15;
  const int kq   = lane >> 4;

  f32x4 acc[4][4];
#pragma unroll
  for (int i = 0; i < 4; i++)
#pragma unroll
    for (int j = 0; j < 4; j++) acc[i][j] = (f32x4){0.f, 0.f, 0.f, 0.f};

  const int row0 = tid >> 2;
  const int cb   = (tid & 3) * 8;
  const size_t aoff = (size_t)(m0 + row0) * K + cb;
  const size_t boff = (size_t)(n0 + row0) * K + cb;

  for (int k0 = 0; k0 < K; k0 += 32) {
    gl2lds16(Ah + aoff + k0,                  sAh + wave * 512);
    gl2lds16(Ah + aoff + k0 + (size_t)64 * K, sAh + 2048 + wave * 512);
    gl2lds16(Al + aoff + k0,                  sAl + wave * 512);
    gl2lds16(Al + aoff + k0 + (size_t)64 * K, sAl + 2048 + wave * 512);
    gl2lds16(Bm + boff + k0,                  sB + wave * 512);
    gl2lds16(Bm + boff + k0 + (size_t)64 * K, sB + 2048 + wave * 512);
    __syncthreads();

    bf16x8 afh[4], afl[4], bfr[4];
#pragma unroll
    for (int i = 0; i < 4; i++) {
      const int ao = (wm + i * 16 + lrow) * 32 + kq * 8;
      afh[i] = *(const bf16x8*)(sAh + ao);
      afl[i] = *(const bf16x8*)(sAl + ao);
      bfr[i] = *(const bf16x8*)(sB + (wn + i * 16 + lrow) * 32 + kq * 8);
    }
#pragma unroll
    for (int i = 0; i < 4; i++)
#pragma unroll
      for (int j = 0; j < 4; j++) {
        acc[i][j] = __builtin_amdgcn_mfma_f32_16x16x32_bf16(afh[i], bfr[j], acc[i][j], 0, 0, 0);
        acc[i][j] = __builtin_amdgcn_mfma_f32_16x16x32_bf16(afl[i], bfr[j], acc[i][j], 0, 0, 0);
      }
    __syncthreads();
  }

  const int f32o = (OMODE == 2) ? *flag : 0;
#pragma unroll
  for (int i = 0; i < 4; i++) {
    const int r0 = m0 + wm + i * 16 + kq * 4;
#pragma unroll
    for (int j = 0; j < 4; j++) {
      const int c = n0 + wn + j * 16 + lrow;
#pragma unroll
      for (int r = 0; r < 4; r++) {
        const size_t idx = (size_t)(r0 + r) * N + c;
        if (f32o) ((float*)C)[idx] = acc[i][j][r];
        else      ((bf16*)C)[idx] = __float2bfloat16(acc[i][j][r]);
      }
    }
  }
}

// ---------------- conv (causal, KW=4) + SiLU + per-head l2norm (f32) -------
__global__ __launch_bounds__(128) void conv_silu_norm(
    const float* __restrict__ mixed, const float* __restrict__ convw,
    float* __restrict__ y) {
  const int g = blockIdx.x;
  const int n = blockIdx.y;
  const int t = n & (T_ - 1);
  const int c = g * 128 + threadIdx.x;

  const float4 w = *(const float4*)(convw + (size_t)c * 4);

  const float* mc = mixed + (size_t)n * CDIM + c;
  float a = mc[0] * w.w;
  if (t >= 1) a += mc[-CDIM] * w.z;
  if (t >= 2) a += mc[-2 * CDIM] * w.y;
  if (t >= 3) a += mc[-3 * CDIM] * w.x;
  float s = a / (1.f + expf(-a));

  if (g < 32) {
    float ss = s * s;
#pragma unroll
    for (int o = 32; o > 0; o >>= 1) ss += __shfl_xor(ss, o);
    __shared__ float red[2];
    if ((threadIdx.x & 63) == 0) red[threadIdx.x >> 6] = ss;
    __syncthreads();
    s *= rsqrtf(red[0] + red[1] + EPSF);
  }
  y[(size_t)n * CDIM + c] = s;
}

// ---------------- gate projections: beta, decay (full f32) -----------------
__global__ __launch_bounds__(256) void gates_kernel(
    const bf16* __restrict__ xh, const bf16* __restrict__ xl,
    const float* __restrict__ w_b, const float* __restrict__ w_a,
    const float* __restrict__ dtb, const float* __restrict__ alog,
    float* __restrict__ beta, float* __restrict__ decay) {
  const int n = blockIdx.x, tid = threadIdx.x;
  __shared__ float xs[DM];
  __shared__ float red[32][8];
  {
    uint4 ph = ((const uint4*)(xh + (size_t)n * DM))[tid];
    uint4 pl = ((const uint4*)(xl + (size_t)n * DM))[tid];
    float h[8], l[8]; up8(ph, h); up8(pl, l);
    const int b = tid * 8;
#pragma unroll
    for (int j = 0; j < 8; j++) xs[b + j] = h[j] + l[j];
  }
  __syncthreads();
  const int hh = tid >> 3, part = tid & 7;
  const float* wrow =
      (hh < 16 ? w_b + (size_t)hh * DM : w_a + (size_t)(hh - 16) * DM) + part * 256;
  const float* xp = xs + part * 256;
  float sum = 0.f;
#pragma unroll 4
  for (int i = 0; i < 256; i += 4) {
    float4 p = *(const float4*)(wrow + i);
    sum += xp[i + 0] * p.x + xp[i + 1] * p.y + xp[i + 2] * p.z + xp[i + 3] * p.w;
  }
  red[hh][part] = sum;
  __syncthreads();
  if (tid < 32) {
    float d = 0.f;
#pragma unroll
    for (int p = 0; p < 8; p++) d += red[tid][p];
    if (tid < 16) {
      beta[(size_t)n * H_ + tid] = 1.f / (1.f + expf(-d));
    } else {
      const int h = tid - 16;
      float u = d + dtb[h];
      float sp = (u > 20.f) ? u : log1pf(expf(u));
      decay[(size_t)n * H_ + h] = expf(-expf(alog[h]) * sp);
    }
  }
}

// ---------------- delta-rule scan: 512-thread blocks, 2 waves/SIMD ---------
// grid (DV/16, H, B), block 512 = 32 kg x 16 vl; each lane holds 4 k
// (contiguous float4, 16B LDS stride = free 2-way aliasing). 8 waves/block
// on 4 SIMDs = 2 waves/SIMD: sibling wave fills dependency stalls.
// Reduction: 4 DPP levels (16-lane rows) + shfl_xor(16) across rows.
__global__ __launch_bounds__(512, 1) void scan_kernel(
    const float* __restrict__ y, const float* __restrict__ beta,
    const float* __restrict__ decay, float* __restrict__ o) {
  const int vb = blockIdx.x, h = blockIdx.y, b = blockIdx.z;
  const int tid = threadIdx.x;
  const int kg = tid & 31;   // k-slice: k = kg*4 .. kg*4+3
  const int vl = tid >> 5;   // v column 0..15

  __shared__ __align__(16) float sq[2][CGRP][128];
  __shared__ __align__(16) float sk[2][CGRP][128];
  __shared__ __align__(16) float sv[2][CGRP][16];
  __shared__ float sd[2][CGRP];
  __shared__ float sb[2][CGRP];

  const size_t rowbase = (size_t)b * T_ * CDIM;
  const int qoff = h * 128;
  const int koff = 2048 + h * 128;
  const int voff = 4096 + h * 128 + vb * 16;
  const float* bb = beta + (size_t)b * T_ * H_ + h;
  const float* db = decay + (size_t)b * T_ * H_ + h;
  float* ob = o + (size_t)b * T_ * (H_ * DV_) + h * 128 + vb * 16 + vl;

  const int ls = tid >> 5;   // staging: step within group (0..15)
  const int lj = tid & 31;   // staging: float4 at [lj*4, lj*4+4)

  float S[4];
#pragma unroll
  for (int j = 0; j < 4; j++) S[j] = 0.f;

  float4 ga, gb, gv4;
  float gdd = 0.f, gbt = 0.f;

#define STAGE_ISSUE(t0)                                                      \
  {                                                                          \
    const float* r = y + rowbase + (size_t)((t0) + ls) * CDIM;               \
    ga = *(const float4*)(r + qoff + lj * 4);                                \
    gb = *(const float4*)(r + koff + lj * 4);                                \
    if (tid < 64)                                                            \
      gv4 = *(const float4*)(y + rowbase + (size_t)((t0) + (tid >> 2)) * CDIM\
                             + voff + (tid & 3) * 4);                        \
    if (tid < 16) gdd = db[(size_t)((t0) + tid) * H_];                       \
    else if (tid < 32) gbt = bb[(size_t)((t0) + tid - 16) * H_];             \
  }

#define STAGE_WRITE(buf)                                                     \
  {                                                                          \
    *(float4*)&sq[buf][ls][lj * 4] = ga;                                     \
    *(float4*)&sk[buf][ls][lj * 4] = gb;                                     \
    if (tid < 64) *(float4*)&sv[buf][tid >> 2][(tid & 3) * 4] = gv4;         \
    if (tid < 16) sd[buf][tid] = gdd;                                        \
    else if (tid < 32) sb[buf][tid - 16] = gbt;                              \
  }

#define READ_STEP(buf, s, qd, kd, vvd, ddd, btd)                             \
  {                                                                          \
    *(float4*)(qd) = *(const float4*)&sq[buf][s][kg * 4];                    \
    *(float4*)(kd) = *(const float4*)&sk[buf][s][kg * 4];                    \
    vvd = sv[buf][s][vl]; ddd = sd[buf][s]; btd = sb[buf][s];                \
  }

  // prime group 0
  STAGE_ISSUE(0);
  STAGE_WRITE(0);
  __syncthreads();

  float q[4], k[4], nq[4], nk[4];
  float vv, dd, bt, nvv, ndd, nbt;
  float pp[CGRP];
  READ_STEP(0, 0, q, k, vv, dd, bt);

  const int NGRP = T_ / CGRP;
  for (int g = 0; g < NGRP; g++) {
    const int cbuf = g & 1, nbuf = cbuf ^ 1;
    const bool more = (g + 1 < NGRP);
    if (more) STAGE_ISSUE((g + 1) * CGRP);
#pragma unroll
    for (int s = 0; s < CGRP; s++) {
      if (s < CGRP - 1) READ_STEP(cbuf, s + 1, nq, nk, nvv, ndd, nbt);
      // kv = k . S, tree + 32-lane rowsum (the serial chain)
      float t0 = fmaf(S[1], k[1], S[0] * k[0]);
      float t1 = fmaf(S[3], k[3], S[2] * k[2]);
      float kv = row_sum32(t0 + t1);
      const float u = fmaf(-dd, kv, vv) * bt;
#pragma unroll
      for (int j = 0; j < 4; j++) S[j] = fmaf(dd, S[j], k[j] * u);
      // op partial only; rowsum + store deferred to group end
      float p0 = fmaf(S[1], q[1], S[0] * q[0]);
      float p1 = fmaf(S[3], q[3], S[2] * q[2]);
      pp[s] = p0 + p1;
      if (s < CGRP - 1) {
#pragma unroll
        for (int j = 0; j < 4; j++) { q[j] = nq[j]; k[j] = nk[j]; }
        vv = nvv; dd = ndd; bt = nbt;
      }
    }
    // deferred: 16 independent rowsums (pipelined) + stores
#pragma unroll
    for (int s = 0; s < CGRP; s++) pp[s] = row_sum32(pp[s]);
    if (kg == 0) {
#pragma unroll
      for (int s = 0; s < CGRP; s++)
        ob[(size_t)(g * CGRP + s) * (H_ * DV_)] = pp[s];
    }
    if (more) {
      STAGE_WRITE(nbuf);
      __syncthreads();
      READ_STEP(nbuf, 0, q, k, vv, dd, bt);
    }
  }
#undef STAGE_ISSUE
#undef STAGE_WRITE
#undef READ_STEP
}

// -------- gated RMSNorm + SiLU(z) gate -> split bf16 (hi + lo) -------------
__global__ __launch_bounds__(128) void norm_gate(
    const float* __restrict__ o, const bf16* __restrict__ z,
    const float* __restrict__ norm_w, bf16* __restrict__ on_hi,
    bf16* __restrict__ on_lo) {
  const int n = blockIdx.x, h = blockIdx.y, v = threadIdx.x;
  const size_t idx = (size_t)n * (H_ * DV_) + h * 128 + v;
  const float ov = o[idx];
  float ss = ov * ov;
#pragma unroll
  for (int w = 32; w > 0; w >>= 1) ss += __shfl_xor(ss, w);
  __shared__ float red[2];
  if ((v & 63) == 0) red[v >> 6] = ss;
  __syncthreads();
  const float ms = (red[0] + red[1]) * (1.f / 128.f);
  const float zv = __bfloat162float(z[idx]);
  const float res = ov * rsqrtf(ms + EPSF) * norm_w[v] *
                    (zv / (1.f + expf(-zv)));
  const bf16 hi = __float2bfloat16(res);
  on_hi[idx] = hi;
  on_lo[idx] = __float2bfloat16(res - __bfloat162float(hi));
}

// ---------------------------------------------------------------------------
extern "C" void kernel_launch(void* const* d_in, const int* in_sizes, int n_in,
                              void* d_out, int out_size, void* d_ws, size_t ws_size,
                              hipStream_t stream) {
  const int NT = B_ * T_;  // 4096
  char* ws = (char*)d_ws;
  int*   flag   = (int*)(ws + FLAG_OFF);
  float* dt_f   = (float*)(ws + DT_OFF);
  float* al_f   = (float*)(ws + AL_OFF);
  float* nw_f   = (float*)(ws + NW_OFF);
  float* cw_f   = (float*)(ws + CW_OFF);
  float* wb_f   = (float*)(ws + WBF_OFF);
  float* wa_f   = (float*)(ws + WAF_OFF);
  float* betab  = (float*)(ws + BETA_OFF);
  float* decayb = (float*)(ws + DEC_OFF);
  bf16*  x_hi   = (bf16*)(ws + XH_OFF);
  bf16*  x_lo   = (bf16*)(ws + XL_OFF);
  bf16*  wq_hi  = (bf16*)(ws + WQH_OFF);
  bf16*  wq_lo  = (bf16*)(ws + WQL_OFF);
  bf16*  wz_bf  = (bf16*)(ws + WZ_OFF);
  float* mixed  = (float*)(ws + MIX_OFF);
  bf16*  wout_bf= (bf16*)(ws + WOUT_OFF);
  bf16*  z      = (bf16*)(ws + Z_OFF);
  float* y      = (float*)(ws + Y_OFF);
  float* o      = (float*)(ws + O_OFF);
  bf16*  on_hi  = (bf16*)(ws + ONH_OFF);
  bf16*  on_lo  = (bf16*)(ws + ONL_OFF);

  // 0. detect input dtype (flag=1 -> f32)
  detect_dtype<<<1, 256, 0, stream>>>((const unsigned short*)d_in[0], flag);

  // 1. canonicalize
  canon_f32<<<1, 256, 0, stream>>>(d_in[6], dt_f, 16, flag);
  canon_f32<<<1, 256, 0, stream>>>(d_in[7], al_f, 16, flag);
  canon_f32<<<1, 256, 0, stream>>>(d_in[8], nw_f, 128, flag);
  canon_f32<<<12, 256, 0, stream>>>(d_in[2], cw_f, CDIM * 4, flag);
  canon_f32<<<16, 256, 0, stream>>>(d_in[4], wb_f, H_ * DM, flag);
  canon_f32<<<16, 256, 0, stream>>>(d_in[5], wa_f, H_ * DM, flag);
  canon_split<<<4096, 256, 0, stream>>>(d_in[0], x_hi, x_lo, NT * DM, flag);
  canon_split<<<6144, 256, 0, stream>>>(d_in[1], wq_hi, wq_lo, CDIM * DM, flag);
  canon_bf16<<<2048, 256, 0, stream>>>(d_in[3], wz_bf, H_ * DV_ * DM, flag);
  canon_bf16<<<2048, 256, 0, stream>>>(d_in[9], wout_bf, DM * H_ * DV_, flag);

  // 2. gates (f32-precision beta/decay)
  gates_kernel<<<NT, 256, 0, stream>>>(x_hi, x_lo, wb_f, wa_f, dt_f, al_f,
                                       betab, decayb);
  // 3. mixed = x @ w_qkv^T  (split x split, 3-term) -> f32
  gemm_ss<<<dim3(CDIM / 128, NT / 128), 256, 0, stream>>>(
      x_hi, x_lo, wq_hi, wq_lo, mixed, NT, CDIM, DM);
  // 4. z = x @ w_z^T  (split-A) -> bf16
  gemm_bt_split<0><<<dim3((H_ * DV_) / 128, NT / 128), 256, 0, stream>>>(
      x_hi, x_lo, wz_bf, z, NT, H_ * DV_, DM, flag);
  // 5. conv + SiLU + l2norm -> y f32 (overlays dead x/wq/wz)
  conv_silu_norm<<<dim3(CDIM / 128, NT), 128, 0, stream>>>(mixed, cw_f, y);
  // 6. delta-rule scan -> o f32 (overlays dead mixed)
  scan_kernel<<<dim3(DV_ / 16, H_, B_), 512, 0, stream>>>(y, betab, decayb, o);
  // 7. gated RMSNorm -> on hi/lo (overlays dead y)
  norm_gate<<<dim3(NT, H_), 128, 0, stream>>>(o, z, nw_f, on_hi, on_lo);
  // 8. out = on @ w_out^T (split-A, dual-dtype out)
  gemm_bt_split<2><<<dim3(DM / 128, NT / 128), 256, 0, stream>>>(
      on_hi, on_lo, wout_bf, d_out, NT, DM, H_ * DV_, flag);
}

// Round 9
// 1176.256 us; speedup vs baseline: 1.0671x; 1.0671x over previous
//
#include <hip/hip_runtime.h>
#include <hip/hip_bf16.h>

#define B_   2
#define T_   2048
#define DM   2048
#define H_   16
#define DK_  128
#define DV_  128
#define CDIM 6144
#define EPSF 1e-6f
#define CGRP 16   // scan: timesteps staged per LDS group

typedef __hip_bfloat16 bf16;
typedef short bf16x8 __attribute__((ext_vector_type(8)));
typedef float f32x4 __attribute__((ext_vector_type(4)));

// ---- workspace layout (bytes); peak = 227,540,992 < proven-OK 228,589,568 --
#define FLAG_OFF   0
#define DT_OFF     1024
#define AL_OFF     2048
#define NW_OFF     4096
#define CW_OFF     8192          // 98,304 B -> 106,496
#define WBF_OFF    131072        // f32 131,072 -> 262,144
#define WAF_OFF    262144        // -> 393,216
#define BETA_OFF   393216        // 262,144 -> 655,360
#define DEC_OFF    655360        // -> 917,504
#define XH_OFF     1048576       // 16,777,216 -> 17,825,792
#define XL_OFF     17825792      // -> 34,603,008
#define WQH_OFF    34603008      // 25,165,824 -> 59,768,832
#define WQL_OFF    59768832      // -> 84,934,656
#define WZ_OFF     84934656      // 8,388,608 -> 93,323,264
#define MIX_OFF    101711872     // f32 100,663,296 -> 202,375,168
#define WOUT_OFF   202375168     // 8,388,608 -> 210,763,776
#define Z_OFF      210763776     // bf16 16,777,216 -> 227,540,992 (peak)
#define Y_OFF      1048576       // f32 100,663,296 -> 101,711,872 (overlay)
#define O_OFF      101711872     // f32 33,554,432 -> 135,266,304 (over MIX)
#define ONH_OFF    1048576       // 16,777,216 -> 17,825,792 (over dead Y)
#define ONL_OFF    17825792      // -> 34,603,008

__device__ inline float bf2f(unsigned int u) {
  union { unsigned int i; float f; } v; v.i = u << 16; return v.f;
}
__device__ inline void up8(uint4 p, float* d) {
  d[0] = bf2f(p.x & 0xffffu); d[1] = bf2f(p.x >> 16);
  d[2] = bf2f(p.y & 0xffffu); d[3] = bf2f(p.y >> 16);
  d[4] = bf2f(p.z & 0xffffu); d[5] = bf2f(p.z >> 16);
  d[6] = bf2f(p.w & 0xffffu); d[7] = bf2f(p.w >> 16);
}
__device__ inline void gl2lds16(const bf16* g, bf16* lds) {
  __builtin_amdgcn_global_load_lds(
      (const __attribute__((address_space(1))) unsigned int*)g,
      (__attribute__((address_space(3))) unsigned int*)lds, 16, 0, 0);
}

// DPP butterfly add over a 16-lane row — stays on the VALU pipe.
// (xor16 would need ds_swizzle = LDS pipe on the serial chain: R8 regression.)
template <int CTRL>
__device__ inline float radd(float v) {
  int t = __builtin_amdgcn_update_dpp(0, __float_as_int(v), CTRL, 0xF, 0xF, true);
  return v + __int_as_float(t);
}
__device__ inline float row_sum16(float v) {
  v = radd<0xB1>(v);   // quad_perm [1,0,3,2] : + xor1
  v = radd<0x4E>(v);   // quad_perm [2,3,0,1] : + xor2
  v = radd<0x141>(v);  // row_half_mirror     : + xor4
  v = radd<0x140>(v);  // row_mirror          : + xor8
  return v;
}

// ---------------- dtype detector: flag=1 if inputs are f32 -----------------
__global__ __launch_bounds__(256) void detect_dtype(
    const unsigned short* __restrict__ xh, int* __restrict__ flag) {
  __shared__ int cnt;
  if (threadIdx.x == 0) cnt = 0;
  __syncthreads();
  int c = 0;
  for (int i = threadIdx.x; i < 8192; i += 256) {
    unsigned int e = (xh[i] >> 7) & 0xFFu;
    if (e > 140u) c++;
  }
  atomicAdd(&cnt, c);
  __syncthreads();
  if (threadIdx.x == 0) *flag = (cnt > 512) ? 1 : 0;
}

// ---------------- fused canonicalize: 10 segments in one launch ------------
// mode 0: ->f32, mode 1: ->bf16, mode 2: ->split(hi,lo)
__device__ inline void canon_seg(const void* in, char* d0, char* d1, int n,
                                 int mode, int f32in, int i) {
  if (i >= n) return;
  float v[8];
  if (f32in) {
    const float* f = (const float*)in;
    *(float4*)(v)     = *(const float4*)(f + i);
    *(float4*)(v + 4) = *(const float4*)(f + i + 4);
  } else {
    up8(*(const uint4*)((const bf16*)in + i), v);
  }
  if (mode == 0) {
    *(float4*)((float*)d0 + i)     = *(const float4*)(v);
    *(float4*)((float*)d0 + i + 4) = *(const float4*)(v + 4);
  } else if (mode == 1) {
    bf16 t[8];
#pragma unroll
    for (int j = 0; j < 8; j++) t[j] = __float2bfloat16(v[j]);
    *(uint4*)((bf16*)d0 + i) = *(const uint4*)t;
  } else {
    bf16 th[8], tl[8];
#pragma unroll
    for (int j = 0; j < 8; j++) {
      th[j] = __float2bfloat16(v[j]);
      tl[j] = __float2bfloat16(v[j] - __bfloat162float(th[j]));
    }
    *(uint4*)((bf16*)d0 + i) = *(const uint4*)th;
    *(uint4*)((bf16*)d1 + i) = *(const uint4*)tl;
  }
}

// block ranges (2048 elems per block):
// [0,1) dt | [1,2) al | [2,3) nw | [3,15) cw | [15,31) wb | [31,47) wa |
// [47,4143) x-split | [4143,10287) wqkv-split | [10287,12335) wz |
// [12335,14383) wout
__global__ __launch_bounds__(256) void canon_all(
    const void* x, const void* wqkv, const void* cw, const void* wz,
    const void* wb, const void* wa, const void* dt, const void* al,
    const void* nw, const void* wout, char* ws, const int* __restrict__ flag) {
  const int bk = blockIdx.x;
  const int f32in = *flag;
  if (bk < 1)
    canon_seg(dt, ws + DT_OFF, 0, 16, 0, f32in, (bk - 0) * 2048 + threadIdx.x * 8);
  else if (bk < 2)
    canon_seg(al, ws + AL_OFF, 0, 16, 0, f32in, (bk - 1) * 2048 + threadIdx.x * 8);
  else if (bk < 3)
    canon_seg(nw, ws + NW_OFF, 0, 128, 0, f32in, (bk - 2) * 2048 + threadIdx.x * 8);
  else if (bk < 15)
    canon_seg(cw, ws + CW_OFF, 0, CDIM * 4, 0, f32in, (bk - 3) * 2048 + threadIdx.x * 8);
  else if (bk < 31)
    canon_seg(wb, ws + WBF_OFF, 0, H_ * DM, 0, f32in, (bk - 15) * 2048 + threadIdx.x * 8);
  else if (bk < 47)
    canon_seg(wa, ws + WAF_OFF, 0, H_ * DM, 0, f32in, (bk - 31) * 2048 + threadIdx.x * 8);
  else if (bk < 4143)
    canon_seg(x, ws + XH_OFF, ws + XL_OFF, B_ * T_ * DM, 2, f32in,
              (bk - 47) * 2048 + threadIdx.x * 8);
  else if (bk < 10287)
    canon_seg(wqkv, ws + WQH_OFF, ws + WQL_OFF, CDIM * DM, 2, f32in,
              (bk - 4143) * 2048 + threadIdx.x * 8);
  else if (bk < 12335)
    canon_seg(wz, ws + WZ_OFF, 0, H_ * DV_ * DM, 1, f32in,
              (bk - 10287) * 2048 + threadIdx.x * 8);
  else
    canon_seg(wout, ws + WOUT_OFF, 0, DM * H_ * DV_, 1, f32in,
              (bk - 12335) * 2048 + threadIdx.x * 8);
}

// -------- GEMM split x split: C = (Ah+Al)(Bh+Bl)^T (3-term), f32 out -------
__global__ __launch_bounds__(256) void gemm_ss(
    const bf16* __restrict__ Ah, const bf16* __restrict__ Al,
    const bf16* __restrict__ Bh, const bf16* __restrict__ Bl,
    float* __restrict__ C, int M, int N, int K) {
  __shared__ __align__(16) bf16 sAh[128 * 32];
  __shared__ __align__(16) bf16 sAl[128 * 32];
  __shared__ __align__(16) bf16 sBh[128 * 32];
  __shared__ __align__(16) bf16 sBl[128 * 32];
  const int tid  = threadIdx.x;
  const int wave = tid >> 6;
  const int lane = tid & 63;
  const int m0 = blockIdx.y * 128;
  const int n0 = blockIdx.x * 128;
  const int wm = (wave >> 1) * 64;
  const int wn = (wave & 1) * 64;
  const int lrow = lane & 15;
  const int kq   = lane >> 4;

  f32x4 acc[4][4];
#pragma unroll
  for (int i = 0; i < 4; i++)
#pragma unroll
    for (int j = 0; j < 4; j++) acc[i][j] = (f32x4){0.f, 0.f, 0.f, 0.f};

  const int row0 = tid >> 2;
  const int cb   = (tid & 3) * 8;
  const size_t aoff = (size_t)(m0 + row0) * K + cb;
  const size_t boff = (size_t)(n0 + row0) * K + cb;

  for (int k0 = 0; k0 < K; k0 += 32) {
    gl2lds16(Ah + aoff + k0,                  sAh + wave * 512);
    gl2lds16(Ah + aoff + k0 + (size_t)64 * K, sAh + 2048 + wave * 512);
    gl2lds16(Al + aoff + k0,                  sAl + wave * 512);
    gl2lds16(Al + aoff + k0 + (size_t)64 * K, sAl + 2048 + wave * 512);
    gl2lds16(Bh + boff + k0,                  sBh + wave * 512);
    gl2lds16(Bh + boff + k0 + (size_t)64 * K, sBh + 2048 + wave * 512);
    gl2lds16(Bl + boff + k0,                  sBl + wave * 512);
    gl2lds16(Bl + boff + k0 + (size_t)64 * K, sBl + 2048 + wave * 512);
    __syncthreads();

    bf16x8 afh[4], afl[4], bfh[4], bfl[4];
#pragma unroll
    for (int i = 0; i < 4; i++) {
      const int ao = (wm + i * 16 + lrow) * 32 + kq * 8;
      const int bo = (wn + i * 16 + lrow) * 32 + kq * 8;
      afh[i] = *(const bf16x8*)(sAh + ao);
      afl[i] = *(const bf16x8*)(sAl + ao);
      bfh[i] = *(const bf16x8*)(sBh + bo);
      bfl[i] = *(const bf16x8*)(sBl + bo);
    }
#pragma unroll
    for (int i = 0; i < 4; i++)
#pragma unroll
      for (int j = 0; j < 4; j++) {
        acc[i][j] = __builtin_amdgcn_mfma_f32_16x16x32_bf16(afh[i], bfh[j], acc[i][j], 0, 0, 0);
        acc[i][j] = __builtin_amdgcn_mfma_f32_16x16x32_bf16(afh[i], bfl[j], acc[i][j], 0, 0, 0);
        acc[i][j] = __builtin_amdgcn_mfma_f32_16x16x32_bf16(afl[i], bfh[j], acc[i][j], 0, 0, 0);
      }
    __syncthreads();
  }

#pragma unroll
  for (int i = 0; i < 4; i++) {
    const int r0 = m0 + wm + i * 16 + kq * 4;
#pragma unroll
    for (int j = 0; j < 4; j++) {
      const int c = n0 + wn + j * 16 + lrow;
#pragma unroll
      for (int r = 0; r < 4; r++)
        C[(size_t)(r0 + r) * N + c] = acc[i][j][r];
    }
  }
}

// -------- GEMM split-A x single-B: C = (Ah+Al)B^T. OMODE 0: bf16, 2: dual --
template <int OMODE>
__global__ __launch_bounds__(256) void gemm_bt_split(
    const bf16* __restrict__ Ah, const bf16* __restrict__ Al,
    const bf16* __restrict__ Bm, void* __restrict__ C,
    int M, int N, int K, const int* __restrict__ flag) {
  __shared__ __align__(16) bf16 sAh[128 * 32];
  __shared__ __align__(16) bf16 sAl[128 * 32];
  __shared__ __align__(16) bf16 sB[128 * 32];
  const int tid  = threadIdx.x;
  const int wave = tid >> 6;
  const int lane = tid & 63;
  const int m0 = blockIdx.y * 128;
  const int n0 = blockIdx.x * 128;
  const int wm = (wave >> 1) * 64;
  const int wn = (wave & 1) * 64;
  const int lrow = lane & 15;
  const int kq   = lane >> 4;

  f32x4 acc[4][4];
#pragma unroll
  for (int i = 0; i < 4; i++)
#pragma unroll
    for (int j = 0; j < 4; j++) acc[i][j] = (f32x4){0.f, 0.f, 0.f, 0.f};

  const int row0 = tid >> 2;
  const int cb   = (tid & 3) * 8;
  const size_t aoff = (size_t)(m0 + row0) * K + cb;
  const size_t boff = (size_t)(n0 + row0) * K + cb;

  for (int k0 = 0; k0 < K; k0 += 32) {
    gl2lds16(Ah + aoff + k0,                  sAh + wave * 512);
    gl2lds16(Ah + aoff + k0 + (size_t)64 * K, sAh + 2048 + wave * 512);
    gl2lds16(Al + aoff + k0,                  sAl + wave * 512);
    gl2lds16(Al + aoff + k0 + (size_t)64 * K, sAl + 2048 + wave * 512);
    gl2lds16(Bm + boff + k0,                  sB + wave * 512);
    gl2lds16(Bm + boff + k0 + (size_t)64 * K, sB + 2048 + wave * 512);
    __syncthreads();

    bf16x8 afh[4], afl[4], bfr[4];
#pragma unroll
    for (int i = 0; i < 4; i++) {
      const int ao = (wm + i * 16 + lrow) * 32 + kq * 8;
      afh[i] = *(const bf16x8*)(sAh + ao);
      afl[i] = *(const bf16x8*)(sAl + ao);
      bfr[i] = *(const bf16x8*)(sB + (wn + i * 16 + lrow) * 32 + kq * 8);
    }
#pragma unroll
    for (int i = 0; i < 4; i++)
#pragma unroll
      for (int j = 0; j < 4; j++) {
        acc[i][j] = __builtin_amdgcn_mfma_f32_16x16x32_bf16(afh[i], bfr[j], acc[i][j], 0, 0, 0);
        acc[i][j] = __builtin_amdgcn_mfma_f32_16x16x32_bf16(afl[i], bfr[j], acc[i][j], 0, 0, 0);
      }
    __syncthreads();
  }

  const int f32o = (OMODE == 2) ? *flag : 0;
#pragma unroll
  for (int i = 0; i < 4; i++) {
    const int r0 = m0 + wm + i * 16 + kq * 4;
#pragma unroll
    for (int j = 0; j < 4; j++) {
      const int c = n0 + wn + j * 16 + lrow;
#pragma unroll
      for (int r = 0; r < 4; r++) {
        const size_t idx = (size_t)(r0 + r) * N + c;
        if (f32o) ((float*)C)[idx] = acc[i][j][r];
        else      ((bf16*)C)[idx] = __float2bfloat16(acc[i][j][r]);
      }
    }
  }
}

// ---------------- conv (causal, KW=4) + SiLU + per-head l2norm (f32) -------
__global__ __launch_bounds__(128) void conv_silu_norm(
    const float* __restrict__ mixed, const float* __restrict__ convw,
    float* __restrict__ y) {
  const int g = blockIdx.x;
  const int n = blockIdx.y;
  const int t = n & (T_ - 1);
  const int c = g * 128 + threadIdx.x;

  const float4 w = *(const float4*)(convw + (size_t)c * 4);

  const float* mc = mixed + (size_t)n * CDIM + c;
  float a = mc[0] * w.w;
  if (t >= 1) a += mc[-CDIM] * w.z;
  if (t >= 2) a += mc[-2 * CDIM] * w.y;
  if (t >= 3) a += mc[-3 * CDIM] * w.x;
  float s = a / (1.f + expf(-a));

  if (g < 32) {
    float ss = s * s;
#pragma unroll
    for (int o = 32; o > 0; o >>= 1) ss += __shfl_xor(ss, o);
    __shared__ float red[2];
    if ((threadIdx.x & 63) == 0) red[threadIdx.x >> 6] = ss;
    __syncthreads();
    s *= rsqrtf(red[0] + red[1] + EPSF);
  }
  y[(size_t)n * CDIM + c] = s;
}

// ---------------- gate projections: beta, decay (full f32) -----------------
__global__ __launch_bounds__(256) void gates_kernel(
    const bf16* __restrict__ xh, const bf16* __restrict__ xl,
    const float* __restrict__ w_b, const float* __restrict__ w_a,
    const float* __restrict__ dtb, const float* __restrict__ alog,
    float* __restrict__ beta, float* __restrict__ decay) {
  const int n = blockIdx.x, tid = threadIdx.x;
  __shared__ float xs[DM];
  __shared__ float red[32][8];
  {
    uint4 ph = ((const uint4*)(xh + (size_t)n * DM))[tid];
    uint4 pl = ((const uint4*)(xl + (size_t)n * DM))[tid];
    float h[8], l[8]; up8(ph, h); up8(pl, l);
    const int b = tid * 8;
#pragma unroll
    for (int j = 0; j < 8; j++) xs[b + j] = h[j] + l[j];
  }
  __syncthreads();
  const int hh = tid >> 3, part = tid & 7;
  const float* wrow =
      (hh < 16 ? w_b + (size_t)hh * DM : w_a + (size_t)(hh - 16) * DM) + part * 256;
  const float* xp = xs + part * 256;
  float sum = 0.f;
#pragma unroll 4
  for (int i = 0; i < 256; i += 4) {
    float4 p = *(const float4*)(wrow + i);
    sum += xp[i + 0] * p.x + xp[i + 1] * p.y + xp[i + 2] * p.z + xp[i + 3] * p.w;
  }
  red[hh][part] = sum;
  __syncthreads();
  if (tid < 32) {
    float d = 0.f;
#pragma unroll
    for (int p = 0; p < 8; p++) d += red[tid][p];
    if (tid < 16) {
      beta[(size_t)n * H_ + tid] = 1.f / (1.f + expf(-d));
    } else {
      const int h = tid - 16;
      float u = d + dtb[h];
      float sp = (u > 20.f) ? u : log1pf(expf(u));
      decay[(size_t)n * H_ + h] = expf(-expf(alog[h]) * sp);
    }
  }
}

// ---------------- delta-rule scan: LDS-staged, all-DPP, deferred op --------
// R7-proven config: 382 us, 0 bank conflicts. grid (DV/16, H, B), block 256
// = 16 kg x 16 vl; lane k-slice {kg*4..+3} u {64+kg*4..+3} (16B LDS stride,
// free 2-way aliasing); 16-lane all-DPP reduction (VALU pipe only).
__global__ __launch_bounds__(256, 1) void scan_kernel(
    const float* __restrict__ y, const float* __restrict__ beta,
    const float* __restrict__ decay, float* __restrict__ o) {
  const int vb = blockIdx.x, h = blockIdx.y, b = blockIdx.z;
  const int tid = threadIdx.x;
  const int kg = tid & 15;
  const int vl = tid >> 4;

  __shared__ __align__(16) float sq[2][CGRP][128];
  __shared__ __align__(16) float sk[2][CGRP][128];
  __shared__ __align__(16) float sv[2][CGRP][16];
  __shared__ float sd[2][CGRP];
  __shared__ float sb[2][CGRP];

  const size_t rowbase = (size_t)b * T_ * CDIM;
  const int qoff = h * 128;
  const int koff = 2048 + h * 128;
  const int voff = 4096 + h * 128 + vb * 16;
  const float* bb = beta + (size_t)b * T_ * H_ + h;
  const float* db = decay + (size_t)b * T_ * H_ + h;
  float* ob = o + (size_t)b * T_ * (H_ * DV_) + h * 128 + vb * 16 + vl;

  const int ls = tid >> 4;       // staging: step within group
  const int lj = tid & 15;       // staging: float4 pair {lj*4, 64+lj*4}

  float S[8];
#pragma unroll
  for (int j = 0; j < 8; j++) S[j] = 0.f;

  float4 ga0, ga1, gb0, gb1, gv4;
  float gdd = 0.f, gbt = 0.f;

#define STAGE_ISSUE(t0)                                                      \
  {                                                                          \
    const float* r = y + rowbase + (size_t)((t0) + ls) * CDIM;               \
    ga0 = *(const float4*)(r + qoff + lj * 4);                               \
    ga1 = *(const float4*)(r + qoff + 64 + lj * 4);                          \
    gb0 = *(const float4*)(r + koff + lj * 4);                               \
    gb1 = *(const float4*)(r + koff + 64 + lj * 4);                          \
    if (tid < 64)                                                            \
      gv4 = *(const float4*)(y + rowbase + (size_t)((t0) + (tid >> 2)) * CDIM\
                             + voff + (tid & 3) * 4);                        \
    if (tid < 16) gdd = db[(size_t)((t0) + tid) * H_];                       \
    else if (tid < 32) gbt = bb[(size_t)((t0) + tid - 16) * H_];             \
  }

#define STAGE_WRITE(buf)                                                     \
  {                                                                          \
    *(float4*)&sq[buf][ls][lj * 4]      = ga0;                               \
    *(float4*)&sq[buf][ls][64 + lj * 4] = ga1;                               \
    *(float4*)&sk[buf][ls][lj * 4]      = gb0;                               \
    *(float4*)&sk[buf][ls][64 + lj * 4] = gb1;                               \
    if (tid < 64) *(float4*)&sv[buf][tid >> 2][(tid & 3) * 4] = gv4;         \
    if (tid < 16) sd[buf][tid] = gdd;                                        \
    else if (tid < 32) sb[buf][tid - 16] = gbt;                              \
  }

#define READ_STEP(buf, s, qd, kd, vvd, ddd, btd)                             \
  {                                                                          \
    *(float4*)(qd)       = *(const float4*)&sq[buf][s][kg * 4];              \
    *(float4*)((qd) + 4) = *(const float4*)&sq[buf][s][64 + kg * 4];         \
    *(float4*)(kd)       = *(const float4*)&sk[buf][s][kg * 4];              \
    *(float4*)((kd) + 4) = *(const float4*)&sk[buf][s][64 + kg * 4];         \
    vvd = sv[buf][s][vl]; ddd = sd[buf][s]; btd = sb[buf][s];                \
  }

  // prime group 0
  STAGE_ISSUE(0);
  STAGE_WRITE(0);
  __syncthreads();

  float q[8], k[8], nq[8], nk[8];
  float vv, dd, bt, nvv, ndd, nbt;
  float pp[CGRP];
  READ_STEP(0, 0, q, k, vv, dd, bt);

  const int NGRP = T_ / CGRP;
  for (int g = 0; g < NGRP; g++) {
    const int cbuf = g & 1, nbuf = cbuf ^ 1;
    const bool more = (g + 1 < NGRP);
    if (more) STAGE_ISSUE((g + 1) * CGRP);
#pragma unroll
    for (int s = 0; s < CGRP; s++) {
      if (s < CGRP - 1) READ_STEP(cbuf, s + 1, nq, nk, nvv, ndd, nbt);
      // kv = k . S, tree + DPP rowsum (the serial chain)
      float t0 = fmaf(S[1], k[1], S[0] * k[0]);
      float t1 = fmaf(S[3], k[3], S[2] * k[2]);
      float t2 = fmaf(S[5], k[5], S[4] * k[4]);
      float t3 = fmaf(S[7], k[7], S[6] * k[6]);
      float kv = (t0 + t1) + (t2 + t3);
      kv = row_sum16(kv);
      const float u = fmaf(-dd, kv, vv) * bt;
#pragma unroll
      for (int j = 0; j < 8; j++) S[j] = fmaf(dd, S[j], k[j] * u);
      // op partial only; rowsum + store deferred to group end
      float p0 = fmaf(S[1], q[1], S[0] * q[0]);
      float p1 = fmaf(S[3], q[3], S[2] * q[2]);
      float p2 = fmaf(S[5], q[5], S[4] * q[4]);
      float p3 = fmaf(S[7], q[7], S[6] * q[6]);
      pp[s] = (p0 + p1) + (p2 + p3);
      if (s < CGRP - 1) {
#pragma unroll
        for (int j = 0; j < 8; j++) { q[j] = nq[j]; k[j] = nk[j]; }
        vv = nvv; dd = ndd; bt = nbt;
      }
    }
    // deferred: 16 independent rowsums (pipelined DPP) + stores
#pragma unroll
    for (int s = 0; s < CGRP; s++) pp[s] = row_sum16(pp[s]);
    if (kg == 0) {
#pragma unroll
      for (int s = 0; s < CGRP; s++)
        ob[(size_t)(g * CGRP + s) * (H_ * DV_)] = pp[s];
    }
    if (more) {
      STAGE_WRITE(nbuf);
      __syncthreads();
      READ_STEP(nbuf, 0, q, k, vv, dd, bt);
    }
  }
#undef STAGE_ISSUE
#undef STAGE_WRITE
#undef READ_STEP
}

// -------- gated RMSNorm + SiLU(z) gate -> split bf16 (hi + lo) -------------
__global__ __launch_bounds__(128) void norm_gate(
    const float* __restrict__ o, const bf16* __restrict__ z,
    const float* __restrict__ norm_w, bf16* __restrict__ on_hi,
    bf16* __restrict__ on_lo) {
  const int n = blockIdx.x, h = blockIdx.y, v = threadIdx.x;
  const size_t idx = (size_t)n * (H_ * DV_) + h * 128 + v;
  const float ov = o[idx];
  float ss = ov * ov;
#pragma unroll
  for (int w = 32; w > 0; w >>= 1) ss += __shfl_xor(ss, w);
  __shared__ float red[2];
  if ((v & 63) == 0) red[v >> 6] = ss;
  __syncthreads();
  const float ms = (red[0] + red[1]) * (1.f / 128.f);
  const float zv = __bfloat162float(z[idx]);
  const float res = ov * rsqrtf(ms + EPSF) * norm_w[v] *
                    (zv / (1.f + expf(-zv)));
  const bf16 hi = __float2bfloat16(res);
  on_hi[idx] = hi;
  on_lo[idx] = __float2bfloat16(res - __bfloat162float(hi));
}

// ---------------------------------------------------------------------------
extern "C" void kernel_launch(void* const* d_in, const int* in_sizes, int n_in,
                              void* d_out, int out_size, void* d_ws, size_t ws_size,
                              hipStream_t stream) {
  const int NT = B_ * T_;  // 4096
  char* ws = (char*)d_ws;
  int*   flag   = (int*)(ws + FLAG_OFF);
  float* dt_f   = (float*)(ws + DT_OFF);
  float* al_f   = (float*)(ws + AL_OFF);
  float* nw_f   = (float*)(ws + NW_OFF);
  float* cw_f   = (float*)(ws + CW_OFF);
  float* wb_f   = (float*)(ws + WBF_OFF);
  float* wa_f   = (float*)(ws + WAF_OFF);
  float* betab  = (float*)(ws + BETA_OFF);
  float* decayb = (float*)(ws + DEC_OFF);
  bf16*  x_hi   = (bf16*)(ws + XH_OFF);
  bf16*  x_lo   = (bf16*)(ws + XL_OFF);
  bf16*  wq_hi  = (bf16*)(ws + WQH_OFF);
  bf16*  wq_lo  = (bf16*)(ws + WQL_OFF);
  bf16*  wz_bf  = (bf16*)(ws + WZ_OFF);
  float* mixed  = (float*)(ws + MIX_OFF);
  bf16*  wout_bf= (bf16*)(ws + WOUT_OFF);
  bf16*  z      = (bf16*)(ws + Z_OFF);
  float* y      = (float*)(ws + Y_OFF);
  float* o      = (float*)(ws + O_OFF);
  bf16*  on_hi  = (bf16*)(ws + ONH_OFF);
  bf16*  on_lo  = (bf16*)(ws + ONL_OFF);

  // 0. detect input dtype (flag=1 -> f32)
  detect_dtype<<<1, 256, 0, stream>>>((const unsigned short*)d_in[0], flag);

  // 1. canonicalize everything in one launch
  canon_all<<<14383, 256, 0, stream>>>(
      d_in[0], d_in[1], d_in[2], d_in[3], d_in[4], d_in[5], d_in[6], d_in[7],
      d_in[8], d_in[9], ws, flag);

  // 2. gates (f32-precision beta/decay)
  gates_kernel<<<NT, 256, 0, stream>>>(x_hi, x_lo, wb_f, wa_f, dt_f, al_f,
                                       betab, decayb);
  // 3. mixed = x @ w_qkv^T  (split x split, 3-term) -> f32
  gemm_ss<<<dim3(CDIM / 128, NT / 128), 256, 0, stream>>>(
      x_hi, x_lo, wq_hi, wq_lo, mixed, NT, CDIM, DM);
  // 4. z = x @ w_z^T  (split-A) -> bf16
  gemm_bt_split<0><<<dim3((H_ * DV_) / 128, NT / 128), 256, 0, stream>>>(
      x_hi, x_lo, wz_bf, z, NT, H_ * DV_, DM, flag);
  // 5. conv + SiLU + l2norm -> y f32 (overlays dead x/wq/wz)
  conv_silu_norm<<<dim3(CDIM / 128, NT), 128, 0, stream>>>(mixed, cw_f, y);
  // 6. delta-rule scan -> o f32 (overlays dead mixed)
  scan_kernel<<<dim3(DV_ / 16, H_, B_), 256, 0, stream>>>(y, betab, decayb, o);
  // 7. gated RMSNorm -> on hi/lo (overlays dead y)
  norm_gate<<<dim3(NT, H_), 128, 0, stream>>>(o, z, nw_f, on_hi, on_lo);
  // 8. out = on @ w_out^T (split-A, dual-dtype out)
  gemm_bt_split<2><<<dim3(DM / 128, NT / 128), 256, 0, stream>>>(
      on_hi, on_lo, wout_bf, d_out, NT, DM, H_ * DV_, flag);
}